// Round 13
// baseline (125.913 us; speedup 1.0000x reference)
//
#include <hip/hip_runtime.h>
#include <stdint.h>

#define BATCH 32
#define CINX 128
#define FOUT 256
#define NCLS 10

typedef __bf16 bf16x8 __attribute__((ext_vector_type(8)));
typedef float f32x4 __attribute__((ext_vector_type(4)));

#define WT_SLAB 32768                                  // bf16 per (cls,tap)
#define WT_BYTES ((size_t)NCLS * 9 * WT_SLAB * 2)      // 5,898,240
#define Z_BYTES 4096
#define X16_BYTES ((size_t)BATCH * 4096 * CINX * 2)    // 33,554,432
#define WS_NEED (WT_BYTES + Z_BYTES + X16_BYTES)

#define BAR() __builtin_amdgcn_s_barrier()
#define SCHEDBAR() __builtin_amdgcn_sched_barrier(0)
#define LGKM0() asm volatile("s_waitcnt lgkmcnt(0)" ::: "memory")
#define VMW6() asm volatile("s_waitcnt vmcnt(6)" ::: "memory")
#define VMW2() asm volatile("s_waitcnt vmcnt(2)" ::: "memory")
#define VMW0() asm volatile("s_waitcnt vmcnt(0)" ::: "memory")

__device__ __forceinline__ void gl16(const void* g, void* l) {
    __builtin_amdgcn_global_load_lds(
        (const __attribute__((address_space(1))) void*)g,
        (__attribute__((address_space(3))) void*)l, 16, 0, 0);
}

// ---------------------------------------------------------------------------
// prep_all: fused weight transpose+convert and x convert (one launch).
// blocks 0..89: kernel [cls][tap][c][f] f32 -> wt [slab][c32:4][f:256][slot:4]
//   bf16, pre-swizzled: slot holds c-chunk cu = slot ^ ((f>>1)&3).
// blocks 90.. : x f32 -> bf16 flat; block 90 also zeroes the pad slab.
// ---------------------------------------------------------------------------
__global__ __launch_bounds__(256) void prep_all(const float* __restrict__ kin,
                                                __bf16* __restrict__ wt,
                                                const float* __restrict__ x,
                                                __bf16* __restrict__ x16,
                                                __bf16* __restrict__ zbuf) {
    if (blockIdx.x < NCLS * 9) {
        __shared__ __bf16 tile[128 * 260];
        const int slab = blockIdx.x;
        const float* src = kin + (size_t)slab * (CINX * FOUT);
        __bf16* dst = wt + (size_t)slab * WT_SLAB;
        const int t = threadIdx.x;
#pragma unroll
        for (int i = 0; i < 32; ++i) {
            int e4 = t + i * 256;
            int c = e4 >> 6, f4 = e4 & 63;
            f32x4 v = *(const f32x4*)(src + (size_t)e4 * 4);
            __bf16* p = &tile[c * 260 + f4 * 4];
            p[0] = (__bf16)v[0]; p[1] = (__bf16)v[1];
            p[2] = (__bf16)v[2]; p[3] = (__bf16)v[3];
        }
        __syncthreads();
#pragma unroll
        for (int i = 0; i < 16; ++i) {
            int g = t + i * 256;          // 16B unit within slab
            int c32 = g >> 10;            // 32-c quarter
            int u = g & 1023;
            int f = u >> 2, slot = u & 3;
            int cu = slot ^ ((f >> 1) & 3);
            int c0 = c32 * 32 + cu * 8;
            bf16x8 o;
#pragma unroll
            for (int j = 0; j < 8; ++j) o[j] = tile[(c0 + j) * 260 + f];
            *(bf16x8*)(dst + (size_t)g * 8) = o;
        }
    } else {
        const int bx = blockIdx.x - NCLS * 9;
        const size_t u = (size_t)bx * 256 + threadIdx.x;  // 8-elem unit
        f32x4 a = *(const f32x4*)(x + u * 8);
        f32x4 c = *(const f32x4*)(x + u * 8 + 4);
        bf16x8 o;
#pragma unroll
        for (int j = 0; j < 4; ++j) { o[j] = (__bf16)a[j]; o[4 + j] = (__bf16)c[j]; }
        *(bf16x8*)(x16 + u * 8) = o;
        if (bx == 0 && threadIdx.x < 128) {
            bf16x8 z;
#pragma unroll
            for (int j = 0; j < 8; ++j) z[j] = (__bf16)0.f;
            *(bf16x8*)(zbuf + (size_t)threadIdx.x * 8) = z;
        }
    }
}

// ---------------------------------------------------------------------------
// conv_halo: 256px x 256f tile, 36 K-steps of 32c x 1 tap. A staged ONCE per
// c-quarter as a halo'd LDS tile [hpx = row*66+col][slot] (25.3 KB; rows
// y0-1..y0+4, cols -1..64) -> taps are pure LDS-offset reads; per-thread
// gloads drop 144 -> ~52. B quad-buffered (4x16 KB @32768), counted
// vmcnt(2)/step (vmcnt(6) at the 3 cq boundaries), 2 publish barriers only
// where required. 8 waves (2M x 4N), per-wave 128x64, 16x16x32 MFMA, proven
// 0-conflict XOR-swizzled layout on both operands. Full unroll.
// ---------------------------------------------------------------------------
__global__ __launch_bounds__(512, 2) void conv_halo(
    const __bf16* __restrict__ xg16, const int* __restrict__ cls_g,
    const __bf16* __restrict__ wt, const float* __restrict__ bias,
    const __bf16* __restrict__ zbuf, float* __restrict__ out) {
    __shared__ __align__(16) char lds[98304];   // A halo @0 (25344 + pad), B @32768

    const int bid0 = blockIdx.x;
    const int swz  = (bid0 & 7) * 64 + (bid0 >> 3);   // XCD swizzle, bijective
    const int b    = swz >> 4;
    const int pt   = swz & 15;
    const int cls  = cls_g[b];
    const int y0   = pt << 2;

    const int tid  = threadIdx.x;
    const int lane = tid & 63;
    const int wid  = tid >> 6;
    const int wm   = wid >> 2;   // 0..1
    const int wn   = wid & 3;    // 0..3
    const int l15  = lane & 15;
    const int l4   = lane >> 4;

    const __bf16* xb   = xg16 + (size_t)b * 4096 * CINX;
    const __bf16* wcls = wt + (size_t)cls * 9 * WT_SLAB;
    const char*   ZS   = (const char*)zbuf + (tid & 255) * 16;

    // ---- A-halo staging precompute: 4 uniform units/thread (q = j*512+tid).
    //      Units with q >= 1584 or OOB pixels load zeros; q in [1584,2048)
    //      lands in the LDS pad [25344,32768) -- harmless, keeps vmcnt
    //      counts uniform across waves.
    const __bf16* PAH[4];
    bool okJ[4];
#pragma unroll
    for (int j = 0; j < 4; ++j) {
        const int q = j * 512 + tid;
        const int hpx = q >> 2, slot = q & 3;
        const int row = hpx / 66;
        const int col = hpx - row * 66;
        const int y = y0 + row - 1, xc = col - 1;
        const bool ok = (hpx < 396) && ((unsigned)y < 64u) && ((unsigned)xc < 64u);
        const int chunk = slot ^ ((hpx >> 1) & 3);
        const int yy = ok ? y : 0, xx = ok ? xc : 0;
        PAH[j] = xb + ((size_t)(yy * 64 + xx)) * CINX + chunk * 8;
        okJ[j] = ok;
    }
    auto stageA = [&](int cq2) {
#pragma unroll
        for (int j = 0; j < 4; ++j) {
            const void* src = okJ[j] ? (const void*)(PAH[j] + cq2 * 32)
                                     : (const void*)ZS;
            gl16(src, lds + (j * 512 + tid) * 16);
        }
    };
    auto stageB = [&](int s2) {
        const int tap2 = s2 % 9, cq2 = s2 / 9;
        const __bf16* wsrc = wcls + (size_t)tap2 * WT_SLAB + cq2 * 8192;
        char* dst = lds + 32768 + (s2 & 3) * 16384;
#pragma unroll
        for (int i = 0; i < 2; ++i) {
            const int q = i * 512 + tid;
            gl16(wsrc + (size_t)q * 8, dst + q * 16);
        }
    };

    // ---- fragment addresses ----
    int hpx0[8];   // halo'd pixel index at (dy,dx) = (0,0)
#pragma unroll
    for (int mt = 0; mt < 8; ++mt) {
        const int px = wm * 128 + mt * 16 + l15;
        hpx0[mt] = ((px >> 6) + 1) * 66 + (px & 63) + 1;
    }
    int adB[4];
#pragma unroll
    for (int nt = 0; nt < 4; ++nt) {
        const int f = wn * 64 + nt * 16 + l15;
        adB[nt] = (f * 4 + (l4 ^ ((f >> 1) & 3))) * 16;
    }

    f32x4 acc[8][4];
#pragma unroll
    for (int i = 0; i < 8; ++i)
#pragma unroll
        for (int j = 0; j < 4; ++j)
#pragma unroll
            for (int r = 0; r < 4; ++r) acc[i][j][r] = 0.f;

    // prologue: halo A(cq0) + B(0),B(1) in flight; land A+B(0); publish
    stageA(0);
    stageB(0);
    stageB(1);
    VMW2();
    BAR();
    SCHEDBAR();

#pragma unroll
    for (int s = 0; s < 36; ++s) {
        const int tap = s % 9, cq = s / 9;
        const int dy = tap / 3 - 1, dx = tap % 3 - 1;
        const int D = dy * 66 + dx;
        const bool bound = (tap == 8) && (cq < 3);
        const bool postb = (tap == 0) && (cq > 0);

        if (postb) {          // land halo A(cq); publish before first read
            VMW2();
            BAR();
            SCHEDBAR();
        }

        const char* bb = lds + 32768 + (s & 3) * 16384;
        bf16x8 BF[4], AF0[4], AF1[4];
#pragma unroll
        for (int nt = 0; nt < 4; ++nt)
            BF[nt] = *(const bf16x8*)(bb + adB[nt]);
        auto lda = [&](int mt) {
            const int h = hpx0[mt] + D;
            const int sl = l4 ^ ((h >> 1) & 3);
            return *(const bf16x8*)(lds + h * 64 + sl * 16);
        };
#pragma unroll
        for (int mt = 0; mt < 4; ++mt) AF0[mt] = lda(mt);

        if (bound) {
#pragma unroll
            for (int mt = 0; mt < 4; ++mt) AF1[mt] = lda(mt + 4);
            LGKM0();          // own A reads in regs before overwrite window
            SCHEDBAR();
            BAR();            // all waves done reading A(cq)
            stageA(cq + 1);   // 4 gloads
            if (s < 34) stageB(s + 2);
        } else {
            if (s < 34) stageB(s + 2);
#pragma unroll
            for (int mt = 0; mt < 4; ++mt) AF1[mt] = lda(mt + 4);
        }

        __builtin_amdgcn_s_setprio(1);
#pragma unroll
        for (int mt = 0; mt < 4; ++mt)
#pragma unroll
            for (int nt = 0; nt < 4; ++nt)
                acc[mt][nt] = __builtin_amdgcn_mfma_f32_16x16x32_bf16(
                    AF0[mt], BF[nt], acc[mt][nt], 0, 0, 0);
#pragma unroll
        for (int mt = 0; mt < 4; ++mt)
#pragma unroll
            for (int nt = 0; nt < 4; ++nt)
                acc[mt + 4][nt] = __builtin_amdgcn_mfma_f32_16x16x32_bf16(
                    AF1[mt], BF[nt], acc[mt + 4][nt], 0, 0, 0);
        __builtin_amdgcn_s_setprio(0);

        // publish wait: land B(s+1) (and at boundaries leave A+B(s+2) flying)
        if (bound) {
            VMW6();
        } else if (s < 34) {
            VMW2();
        } else if (s == 34) {
            VMW0();
        }
        if (s < 35) {
            BAR();
            SCHEDBAR();
        }
    }

    // ---- epilogue: bias + f32 store ----
    float bv[4];
#pragma unroll
    for (int nt = 0; nt < 4; ++nt)
        bv[nt] = bias[cls * FOUT + wn * 64 + nt * 16 + l15];

    float* ob = out + ((size_t)b * 4096 + (size_t)pt * 256) * FOUT;
#pragma unroll
    for (int mt = 0; mt < 8; ++mt) {
#pragma unroll
        for (int r = 0; r < 4; ++r) {
            const int row = wm * 128 + mt * 16 + l4 * 4 + r;
            float* orow = ob + (size_t)row * FOUT;
#pragma unroll
            for (int nt = 0; nt < 4; ++nt)
                orow[wn * 64 + nt * 16 + l15] = acc[mt][nt][r] + bv[nt];
        }
    }
}

// ===========================================================================
// Fallback path (round-2 kernels) if ws_size < WS_NEED
// ===========================================================================
__global__ __launch_bounds__(256) void prep_w_fb(const float* __restrict__ kin,
                                                 __bf16* __restrict__ wt) {
    __shared__ __bf16 tile[128 * 260];
    const int slab = blockIdx.x;
    const float* src = kin + (size_t)slab * (CINX * FOUT);
    __bf16* dst = wt + (size_t)slab * (16 * 256 * 8);
    const int t = threadIdx.x;
#pragma unroll
    for (int i = 0; i < 32; ++i) {
        int e4 = t + i * 256;
        int c = e4 >> 6, f4 = e4 & 63;
        f32x4 v = *(const f32x4*)(src + (size_t)e4 * 4);
        __bf16* p = &tile[c * 260 + f4 * 4];
        p[0] = (__bf16)v[0]; p[1] = (__bf16)v[1];
        p[2] = (__bf16)v[2]; p[3] = (__bf16)v[3];
    }
    __syncthreads();
#pragma unroll
    for (int i = 0; i < 16; ++i) {
        int g = t + i * 256;
        int cu = g >> 8, f = g & 255;
        bf16x8 o;
#pragma unroll
        for (int j = 0; j < 8; ++j) o[j] = tile[(cu * 8 + j) * 260 + f];
        *(bf16x8*)(dst + (size_t)g * 8) = o;
    }
}

__global__ __launch_bounds__(512, 2) void conv_fb(
    const float* __restrict__ xg, const int* __restrict__ cls_g,
    const __bf16* __restrict__ wt, const float* __restrict__ bias,
    float* __restrict__ out) {
    __shared__ __align__(16) __bf16 ldsA[2][8 * 256 * 8];
    __shared__ __align__(16) __bf16 ldsB[2][8 * 256 * 8];
    const int bid0 = blockIdx.x;
    const int swz = (bid0 & 7) * 64 + (bid0 >> 3);
    const int b = swz >> 4, pt = swz & 15;
    const int cls = cls_g[b];
    const int y0 = pt << 2;
    const int tid = threadIdx.x, lane = tid & 63, wid = tid >> 6;
    const int wm = wid >> 2, wn = wid & 3, l15 = lane & 15, l4 = lane >> 4;
    const float* xb = xg + (size_t)b * 4096 * CINX;
    const __bf16* wcls = wt + (size_t)cls * 9 * (16 * 256 * 8);
    const int tpx = tid >> 1, tch = (tid & 1) * 32;
    const int py = tpx >> 6, px_ = tpx & 63;
    f32x4 acc[8][4];
#pragma unroll
    for (int i = 0; i < 8; ++i)
#pragma unroll
        for (int j = 0; j < 4; ++j)
#pragma unroll
            for (int r = 0; r < 4; ++r) acc[i][j][r] = 0.f;
    f32x4 va[8];
    auto issueB = [&](int s, int buf) {
        const int tap = s >> 1, chalf = (s & 1) << 6;
        const __bf16* wsrc = wcls + (size_t)tap * (16 * 256 * 8) + chalf * 256;
#pragma unroll
        for (int i = 0; i < 4; ++i) {
            const int u = i * 512 + tid;
            gl16(wsrc + (size_t)u * 8, &ldsB[buf][(size_t)u * 8]);
        }
    };
    auto issueA = [&](int s) {
        const int tap = s >> 1, chalf = (s & 1) << 6;
        const int dy = tap / 3 - 1, dx = tap % 3 - 1;
        const int gy = y0 + py + dy, gx = px_ + dx;
        const bool valid = ((unsigned)gy < 64u) && ((unsigned)gx < 64u);
        const float* src = xb + ((size_t)(gy * 64 + gx)) * CINX + chalf + tch;
        if (valid) {
#pragma unroll
            for (int j2 = 0; j2 < 8; ++j2) va[j2] = *(const f32x4*)(src + j2 * 4);
        } else {
#pragma unroll
            for (int j2 = 0; j2 < 8; ++j2)
#pragma unroll
                for (int q = 0; q < 4; ++q) va[j2][q] = 0.f;
        }
    };
    auto writeA = [&](int buf) {
#pragma unroll
        for (int j = 0; j < 4; ++j) {
            bf16x8 pk;
#pragma unroll
            for (int q = 0; q < 4; ++q) {
                pk[q] = (__bf16)va[2 * j][q];
                pk[4 + q] = (__bf16)va[2 * j + 1][q];
            }
            const int u = ((tid & 1) * 4 + j) * 256 + tpx;
            *(bf16x8*)(&ldsA[buf][(size_t)u * 8]) = pk;
        }
    };
    auto compute = [&](int buf) {
#pragma unroll
        for (int kk = 0; kk < 2; ++kk) {
            const int cu = kk * 4 + l4;
            bf16x8 afr[8], bfr[4];
#pragma unroll
            for (int mt = 0; mt < 8; ++mt)
                afr[mt] = *(const bf16x8*)(
                    &ldsA[buf][(size_t)(cu * 256 + wm * 128 + mt * 16 + l15) * 8]);
#pragma unroll
            for (int nt = 0; nt < 4; ++nt)
                bfr[nt] = *(const bf16x8*)(
                    &ldsB[buf][(size_t)(cu * 256 + wn * 64 + nt * 16 + l15) * 8]);
#pragma unroll
            for (int mt = 0; mt < 8; ++mt)
#pragma unroll
                for (int nt = 0; nt < 4; ++nt)
                    acc[mt][nt] = __builtin_amdgcn_mfma_f32_16x16x32_bf16(
                        afr[mt], bfr[nt], acc[mt][nt], 0, 0, 0);
        }
    };
    issueB(0, 0);
    issueA(0);
    writeA(0);
    __syncthreads();
    int cur = 0;
    for (int s = 0; s < 17; ++s) {
        issueB(s + 1, cur ^ 1);
        issueA(s + 1);
        compute(cur);
        writeA(cur ^ 1);
        __syncthreads();
        cur ^= 1;
    }
    compute(cur);
    float bv[4];
#pragma unroll
    for (int nt = 0; nt < 4; ++nt)
        bv[nt] = bias[cls * FOUT + wn * 64 + nt * 16 + l15];
    float* ob = out + ((size_t)b * 4096 + (size_t)pt * 256) * FOUT;
#pragma unroll
    for (int mt = 0; mt < 8; ++mt) {
#pragma unroll
        for (int r = 0; r < 4; ++r) {
            const int row = wm * 128 + mt * 16 + l4 * 4 + r;
            float* orow = ob + (size_t)row * FOUT;
#pragma unroll
            for (int nt = 0; nt < 4; ++nt)
                orow[wn * 64 + nt * 16 + l15] = acc[mt][nt][r] + bv[nt];
        }
    }
}

extern "C" void kernel_launch(void* const* d_in, const int* in_sizes, int n_in,
                              void* d_out, int out_size, void* d_ws, size_t ws_size,
                              hipStream_t stream) {
    const float* x       = (const float*)d_in[0];
    const int*   classes = (const int*)d_in[1];
    const float* kin     = (const float*)d_in[2];
    const float* bias    = (const float*)d_in[3];
    float* out = (float*)d_out;

    char* ws = (char*)d_ws;
    __bf16* wt   = (__bf16*)ws;
    __bf16* zbuf = (__bf16*)(ws + WT_BYTES);
    __bf16* x16  = (__bf16*)(ws + WT_BYTES + Z_BYTES);

    if (ws_size >= WS_NEED) {
        prep_all<<<dim3(NCLS * 9 + 8192), dim3(256), 0, stream>>>(kin, wt, x,
                                                                  x16, zbuf);
        conv_halo<<<dim3(512), dim3(512), 0, stream>>>(x16, classes, wt, bias,
                                                       zbuf, out);
    } else {
        prep_w_fb<<<dim3(NCLS * 9), dim3(256), 0, stream>>>(kin, wt);
        conv_fb<<<dim3(512), dim3(512), 0, stream>>>(x, classes, wt, bias, out);
    }
}

// Round 14
// 97.675 us; speedup vs baseline: 1.2891x; 1.2891x over previous
//
#include <hip/hip_runtime.h>
#include <stdint.h>

#define BATCH 32
#define CINX 128
#define FOUT 256
#define NCLS 10

typedef __bf16 bf16x8 __attribute__((ext_vector_type(8)));
typedef float f32x4 __attribute__((ext_vector_type(4)));

#define WT_SLAB 32768                                  // bf16 per (cls,tap)
#define WT_BYTES ((size_t)NCLS * 9 * WT_SLAB * 2)      // 5,898,240
#define Z_BYTES 4096
#define X16_BYTES ((size_t)BATCH * 4096 * CINX * 2)    // 33,554,432
#define WS_NEED (WT_BYTES + Z_BYTES + X16_BYTES)

#define BAR() __builtin_amdgcn_s_barrier()
#define SCHEDBAR() __builtin_amdgcn_sched_barrier(0)
#define VMW4() asm volatile("s_waitcnt vmcnt(4)" ::: "memory")
#define VMW0() asm volatile("s_waitcnt vmcnt(0)" ::: "memory")

__device__ __forceinline__ void gl16(const void* g, void* l) {
    __builtin_amdgcn_global_load_lds(
        (const __attribute__((address_space(1))) void*)g,
        (__attribute__((address_space(3))) void*)l, 16, 0, 0);
}

// ---------------------------------------------------------------------------
// prep_all: fused weight transpose+convert and x convert (one launch).
// blocks 0..89: kernel [cls][tap][c][f] f32 -> wt [slab][c32:4][f:256][slot:4]
//   bf16, pre-swizzled: slot holds c-chunk cu = slot ^ ((f>>1)&3).
// blocks 90.. : x f32 -> bf16 flat; block 90 also zeroes the pad slab.
// ---------------------------------------------------------------------------
__global__ __launch_bounds__(256) void prep_all(const float* __restrict__ kin,
                                                __bf16* __restrict__ wt,
                                                const float* __restrict__ x,
                                                __bf16* __restrict__ x16,
                                                __bf16* __restrict__ zbuf) {
    if (blockIdx.x < NCLS * 9) {
        __shared__ __bf16 tile[128 * 260];
        const int slab = blockIdx.x;
        const float* src = kin + (size_t)slab * (CINX * FOUT);
        __bf16* dst = wt + (size_t)slab * WT_SLAB;
        const int t = threadIdx.x;
#pragma unroll
        for (int i = 0; i < 32; ++i) {
            int e4 = t + i * 256;
            int c = e4 >> 6, f4 = e4 & 63;
            f32x4 v = *(const f32x4*)(src + (size_t)e4 * 4);
            __bf16* p = &tile[c * 260 + f4 * 4];
            p[0] = (__bf16)v[0]; p[1] = (__bf16)v[1];
            p[2] = (__bf16)v[2]; p[3] = (__bf16)v[3];
        }
        __syncthreads();
#pragma unroll
        for (int i = 0; i < 16; ++i) {
            int g = t + i * 256;          // 16B unit within slab
            int c32 = g >> 10;            // 32-c quarter
            int u = g & 1023;
            int f = u >> 2, slot = u & 3;
            int cu = slot ^ ((f >> 1) & 3);
            int c0 = c32 * 32 + cu * 8;
            bf16x8 o;
#pragma unroll
            for (int j = 0; j < 8; ++j) o[j] = tile[(c0 + j) * 260 + f];
            *(bf16x8*)(dst + (size_t)g * 8) = o;
        }
    } else {
        const int bx = blockIdx.x - NCLS * 9;
        const size_t u = (size_t)bx * 256 + threadIdx.x;  // 8-elem unit
        f32x4 a = *(const f32x4*)(x + u * 8);
        f32x4 c = *(const f32x4*)(x + u * 8 + 4);
        bf16x8 o;
#pragma unroll
        for (int j = 0; j < 4; ++j) { o[j] = (__bf16)a[j]; o[4 + j] = (__bf16)c[j]; }
        *(bf16x8*)(x16 + u * 8) = o;
        if (bx == 0 && threadIdx.x < 128) {
            bf16x8 z;
#pragma unroll
            for (int j = 0; j < 8; ++j) z[j] = (__bf16)0.f;
            *(bf16x8*)(zbuf + (size_t)threadIdx.x * 8) = z;
        }
    }
}

// ---------------------------------------------------------------------------
// conv16u (round-8 verified best, final): 256px x 256f tile, 18 K-steps of
// BK=64 (2x32-c quarters), 8 waves (2M x 4N), per-wave 128x64 via 16x16x32
// MFMA (0-conflict px-major layout + XOR swizzle). Quad-buffered LDS arena
// (A 4x16KB @0, B 4x16KB @64KB). 4 phases/step, 2 publish barriers, counted
// vmcnt(4), one-phase-ahead fragment-register prefetch, spread staging
// (2+2+2+2), full unroll, precomputed vmask/pointers/ds-addresses. Plain
// cached stores (nt measured -15%); halo staging measured -33%; persistence
// measured -42% -- this structure is the session optimum (conv ~81 us,
// MfmaUtil ~40%, ~950 TF-effective).
// ---------------------------------------------------------------------------
__global__ __launch_bounds__(512, 2) void conv16u(
    const __bf16* __restrict__ xg16, const int* __restrict__ cls_g,
    const __bf16* __restrict__ wt, const float* __restrict__ bias,
    const __bf16* __restrict__ zbuf, float* __restrict__ out) {
    __shared__ __align__(16) char lds[131072];

    const int bid0 = blockIdx.x;
    const int swz  = (bid0 & 7) * 64 + (bid0 >> 3);   // XCD swizzle, bijective
    const int b    = swz >> 4;
    const int pt   = swz & 15;
    const int cls  = cls_g[b];
    const int y0   = pt << 2;

    const int tid  = threadIdx.x;
    const int lane = tid & 63;
    const int wid  = tid >> 6;
    const int wm   = wid >> 2;   // 0..1
    const int wn   = wid & 3;    // 0..3
    const int l15  = lane & 15;
    const int l4   = lane >> 4;

    const __bf16* xb   = xg16 + (size_t)b * 4096 * CINX;
    const __bf16* wcls = wt + (size_t)cls * 9 * WT_SLAB;

    // ---- staging precompute (i=0,1 -> unit u = i*512+tid) ----
    const __bf16* PA[2];
    const __bf16* WB[2];
    const __bf16* ZS[2];
    int vmask[2];
    int dstu[2];
#pragma unroll
    for (int i = 0; i < 2; ++i) {
        const int u = i * 512 + tid;
        const int px = u >> 2, slot = u & 3;
        const int py = px >> 6, gx = px & 63;
        const int cuoff = (slot ^ ((px >> 1) & 3)) * 8;
        const int ay = y0 + py;
        PA[i] = xb + ((size_t)(ay * 64 + gx)) * CINX + cuoff;
        WB[i] = wcls + (size_t)u * 8;
        ZS[i] = zbuf + (size_t)(u & 63) * 8;
        dstu[i] = u * 16;
        int m = 0;
#pragma unroll
        for (int tap = 0; tap < 9; ++tap) {
            const int dy = tap / 3 - 1, dx = tap % 3 - 1;
            const int yy = ay + dy, xx = gx + dx;
            m |= ((((unsigned)yy < 64u) && ((unsigned)xx < 64u)) ? 1 : 0) << tap;
        }
        vmask[i] = m;
    }

    // ---- fragment ds_read byte addresses (within a 16KB buffer) ----
    int adA[8], adB[4];
#pragma unroll
    for (int mt = 0; mt < 8; ++mt) {
        const int px = wm * 128 + mt * 16 + l15;
        adA[mt] = (px * 4 + (l4 ^ ((px >> 1) & 3))) * 16;
    }
#pragma unroll
    for (int nt = 0; nt < 4; ++nt) {
        const int f = wn * 64 + nt * 16 + l15;
        adB[nt] = 65536 + (f * 4 + (l4 ^ ((f >> 1) & 3))) * 16;
    }

    f32x4 acc[8][4];
#pragma unroll
    for (int i = 0; i < 8; ++i)
#pragma unroll
        for (int j = 0; j < 4; ++j)
#pragma unroll
            for (int r = 0; r < 4; ++r) acc[i][j][r] = 0.f;

    // split staging: 2 A gloads / 2 B gloads per call
    auto stageA = [&](int s2, int kk) {
        const int pk  = (s2 & 1) * 2 + kk;
        const int tap = s2 >> 1;
        const int dy = tap / 3 - 1, dx = tap % 3 - 1;
        const int cq = (s2 & 1) * 2 + kk;
        const int aoff = (dy * 64 + dx) * CINX + cq * 32;
#pragma unroll
        for (int i = 0; i < 2; ++i) {
            const __bf16* src = ((vmask[i] >> tap) & 1) ? (PA[i] + aoff) : ZS[i];
            gl16(src, lds + pk * 16384 + dstu[i]);
        }
    };
    auto stageB = [&](int s2, int kk) {
        const int pk = (s2 & 1) * 2 + kk;
        const int cq = (s2 & 1) * 2 + kk;
        const size_t woff = (size_t)(s2 >> 1) * WT_SLAB + (size_t)cq * 8192;
#pragma unroll
        for (int i = 0; i < 2; ++i)
            gl16(WB[i] + woff, lds + 65536 + pk * 16384 + dstu[i]);
    };

    // double-buffered fragment registers, one-phase-ahead prefetch
    bf16x8 AA[2][4], BB[2][4];
    auto rdA = [&](int set, int pk, int mh) {
#pragma unroll
        for (int mt = 0; mt < 4; ++mt)
            AA[set][mt] = *(const bf16x8*)(lds + pk * 16384 + adA[mh * 4 + mt]);
    };
    auto rdB = [&](int set, int pk) {
#pragma unroll
        for (int nt = 0; nt < 4; ++nt)
            BB[set][nt] = *(const bf16x8*)(lds + pk * 16384 + adB[nt]);
    };
    auto mm = [&](int aset, int bset, int mh) {
        __builtin_amdgcn_s_setprio(1);
#pragma unroll
        for (int mt = 0; mt < 4; ++mt)
#pragma unroll
            for (int nt = 0; nt < 4; ++nt)
                acc[mh * 4 + mt][nt] = __builtin_amdgcn_mfma_f32_16x16x32_bf16(
                    AA[aset][mt], BB[bset][nt], acc[mh * 4 + mt][nt], 0, 0, 0);
        __builtin_amdgcn_s_setprio(0);
    };

    // prologue: 8 loads in flight; land k0; publish; prefetch first frags
    stageA(0, 0); stageB(0, 0);
    stageA(0, 1); stageB(0, 1);
    VMW4();
    BAR();
    SCHEDBAR();
    rdB(0, 0);
    rdA(0, 0, 0);

#pragma unroll
    for (int s = 0; s < 17; ++s) {
        const int pk0 = (s & 1) * 2;
        const int pk1 = pk0 + 1;
        const int pkn = ((s + 1) & 1) * 2;
        // ph0: prefetch A(k0,mh1)->set1; issue A(s+1,k0); mm(k0,mh0)
        rdA(1, pk0, 1);
        stageA(s + 1, 0);
        mm(0, 0, 0);
        // ph1: issue B(s+1,k0); land [s,k1]; publish; prefetch B(k1),A(k1,mh0)
        stageB(s + 1, 0);
        VMW4();
        BAR();
        SCHEDBAR();
        rdB(1, pk1);
        rdA(0, pk1, 0);
        mm(1, 0, 1);
        // ph2: prefetch A(k1,mh1)->set1; issue A(s+1,k1); mm(k1,mh0)
        rdA(1, pk1, 1);
        stageA(s + 1, 1);
        mm(0, 1, 0);
        // ph3: issue B(s+1,k1); land [s+1,k0]; publish; prefetch next k0 frags
        stageB(s + 1, 1);
        VMW4();
        BAR();
        SCHEDBAR();
        rdB(0, pkn);
        rdA(0, pkn, 0);
        mm(1, 1, 1);
    }
    // peeled last step (s = 17, pk 2/3): drain instead of count
    rdA(1, 2, 1);
    mm(0, 0, 0);
    VMW0();
    BAR();
    SCHEDBAR();
    rdB(1, 3);
    rdA(0, 3, 0);
    mm(1, 0, 1);
    rdA(1, 3, 1);
    mm(0, 1, 0);
    mm(1, 1, 1);

    // ---- epilogue: bias + f32 store ----
    float bv[4];
#pragma unroll
    for (int nt = 0; nt < 4; ++nt)
        bv[nt] = bias[cls * FOUT + wn * 64 + nt * 16 + l15];

    float* ob = out + ((size_t)b * 4096 + (size_t)pt * 256) * FOUT;
#pragma unroll
    for (int mt = 0; mt < 8; ++mt) {
#pragma unroll
        for (int r = 0; r < 4; ++r) {
            const int row = wm * 128 + mt * 16 + l4 * 4 + r;
            float* orow = ob + (size_t)row * FOUT;
#pragma unroll
            for (int nt = 0; nt < 4; ++nt)
                orow[wn * 64 + nt * 16 + l15] = acc[mt][nt][r] + bv[nt];
        }
    }
}

// ===========================================================================
// Fallback path (round-2 kernels) if ws_size < WS_NEED
// ===========================================================================
__global__ __launch_bounds__(256) void prep_w_fb(const float* __restrict__ kin,
                                                 __bf16* __restrict__ wt) {
    __shared__ __bf16 tile[128 * 260];
    const int slab = blockIdx.x;
    const float* src = kin + (size_t)slab * (CINX * FOUT);
    __bf16* dst = wt + (size_t)slab * (16 * 256 * 8);
    const int t = threadIdx.x;
#pragma unroll
    for (int i = 0; i < 32; ++i) {
        int e4 = t + i * 256;
        int c = e4 >> 6, f4 = e4 & 63;
        f32x4 v = *(const f32x4*)(src + (size_t)e4 * 4);
        __bf16* p = &tile[c * 260 + f4 * 4];
        p[0] = (__bf16)v[0]; p[1] = (__bf16)v[1];
        p[2] = (__bf16)v[2]; p[3] = (__bf16)v[3];
    }
    __syncthreads();
#pragma unroll
    for (int i = 0; i < 16; ++i) {
        int g = t + i * 256;
        int cu = g >> 8, f = g & 255;
        bf16x8 o;
#pragma unroll
        for (int j = 0; j < 8; ++j) o[j] = tile[(cu * 8 + j) * 260 + f];
        *(bf16x8*)(dst + (size_t)g * 8) = o;
    }
}

__global__ __launch_bounds__(512, 2) void conv_fb(
    const float* __restrict__ xg, const int* __restrict__ cls_g,
    const __bf16* __restrict__ wt, const float* __restrict__ bias,
    float* __restrict__ out) {
    __shared__ __align__(16) __bf16 ldsA[2][8 * 256 * 8];
    __shared__ __align__(16) __bf16 ldsB[2][8 * 256 * 8];
    const int bid0 = blockIdx.x;
    const int swz = (bid0 & 7) * 64 + (bid0 >> 3);
    const int b = swz >> 4, pt = swz & 15;
    const int cls = cls_g[b];
    const int y0 = pt << 2;
    const int tid = threadIdx.x, lane = tid & 63, wid = tid >> 6;
    const int wm = wid >> 2, wn = wid & 3, l15 = lane & 15, l4 = lane >> 4;
    const float* xb = xg + (size_t)b * 4096 * CINX;
    const __bf16* wcls = wt + (size_t)cls * 9 * (16 * 256 * 8);
    const int tpx = tid >> 1, tch = (tid & 1) * 32;
    const int py = tpx >> 6, px_ = tpx & 63;
    f32x4 acc[8][4];
#pragma unroll
    for (int i = 0; i < 8; ++i)
#pragma unroll
        for (int j = 0; j < 4; ++j)
#pragma unroll
            for (int r = 0; r < 4; ++r) acc[i][j][r] = 0.f;
    f32x4 va[8];
    auto issueB = [&](int s, int buf) {
        const int tap = s >> 1, chalf = (s & 1) << 6;
        const __bf16* wsrc = wcls + (size_t)tap * (16 * 256 * 8) + chalf * 256;
#pragma unroll
        for (int i = 0; i < 4; ++i) {
            const int u = i * 512 + tid;
            gl16(wsrc + (size_t)u * 8, &ldsB[buf][(size_t)u * 8]);
        }
    };
    auto issueA = [&](int s) {
        const int tap = s >> 1, chalf = (s & 1) << 6;
        const int dy = tap / 3 - 1, dx = tap % 3 - 1;
        const int gy = y0 + py + dy, gx = px_ + dx;
        const bool valid = ((unsigned)gy < 64u) && ((unsigned)gx < 64u);
        const float* src = xb + ((size_t)(gy * 64 + gx)) * CINX + chalf + tch;
        if (valid) {
#pragma unroll
            for (int j2 = 0; j2 < 8; ++j2) va[j2] = *(const f32x4*)(src + j2 * 4);
        } else {
#pragma unroll
            for (int j2 = 0; j2 < 8; ++j2)
#pragma unroll
                for (int q = 0; q < 4; ++q) va[j2][q] = 0.f;
        }
    };
    auto writeA = [&](int buf) {
#pragma unroll
        for (int j = 0; j < 4; ++j) {
            bf16x8 pk;
#pragma unroll
            for (int q = 0; q < 4; ++q) {
                pk[q] = (__bf16)va[2 * j][q];
                pk[4 + q] = (__bf16)va[2 * j + 1][q];
            }
            const int u = ((tid & 1) * 4 + j) * 256 + tpx;
            *(bf16x8*)(&ldsA[buf][(size_t)u * 8]) = pk;
        }
    };
    auto compute = [&](int buf) {
#pragma unroll
        for (int kk = 0; kk < 2; ++kk) {
            const int cu = kk * 4 + l4;
            bf16x8 afr[8], bfr[4];
#pragma unroll
            for (int mt = 0; mt < 8; ++mt)
                afr[mt] = *(const bf16x8*)(
                    &ldsA[buf][(size_t)(cu * 256 + wm * 128 + mt * 16 + l15) * 8]);
#pragma unroll
            for (int nt = 0; nt < 4; ++nt)
                bfr[nt] = *(const bf16x8*)(
                    &ldsB[buf][(size_t)(cu * 256 + wn * 64 + nt * 16 + l15) * 8]);
#pragma unroll
            for (int mt = 0; mt < 8; ++mt)
#pragma unroll
                for (int nt = 0; nt < 4; ++nt)
                    acc[mt][nt] = __builtin_amdgcn_mfma_f32_16x16x32_bf16(
                        afr[mt], bfr[nt], acc[mt][nt], 0, 0, 0);
        }
    };
    issueB(0, 0);
    issueA(0);
    writeA(0);
    __syncthreads();
    int cur = 0;
    for (int s = 0; s < 17; ++s) {
        issueB(s + 1, cur ^ 1);
        issueA(s + 1);
        compute(cur);
        writeA(cur ^ 1);
        __syncthreads();
        cur ^= 1;
    }
    compute(cur);
    float bv[4];
#pragma unroll
    for (int nt = 0; nt < 4; ++nt)
        bv[nt] = bias[cls * FOUT + wn * 64 + nt * 16 + l15];
    float* ob = out + ((size_t)b * 4096 + (size_t)pt * 256) * FOUT;
#pragma unroll
    for (int mt = 0; mt < 8; ++mt) {
#pragma unroll
        for (int r = 0; r < 4; ++r) {
            const int row = wm * 128 + mt * 16 + l4 * 4 + r;
            float* orow = ob + (size_t)row * FOUT;
#pragma unroll
            for (int nt = 0; nt < 4; ++nt)
                orow[wn * 64 + nt * 16 + l15] = acc[mt][nt][r] + bv[nt];
        }
    }
}

extern "C" void kernel_launch(void* const* d_in, const int* in_sizes, int n_in,
                              void* d_out, int out_size, void* d_ws, size_t ws_size,
                              hipStream_t stream) {
    const float* x       = (const float*)d_in[0];
    const int*   classes = (const int*)d_in[1];
    const float* kin     = (const float*)d_in[2];
    const float* bias    = (const float*)d_in[3];
    float* out = (float*)d_out;

    char* ws = (char*)d_ws;
    __bf16* wt   = (__bf16*)ws;
    __bf16* zbuf = (__bf16*)(ws + WT_BYTES);
    __bf16* x16  = (__bf16*)(ws + WT_BYTES + Z_BYTES);

    if (ws_size >= WS_NEED) {
        prep_all<<<dim3(NCLS * 9 + 8192), dim3(256), 0, stream>>>(kin, wt, x,
                                                                  x16, zbuf);
        conv16u<<<dim3(512), dim3(512), 0, stream>>>(x16, classes, wt, bias,
                                                     zbuf, out);
    } else {
        prep_w_fb<<<dim3(NCLS * 9), dim3(256), 0, stream>>>(kin, wt);
        conv_fb<<<dim3(512), dim3(512), 0, stream>>>(x, classes, wt, bias, out);
    }
}